// Round 15
// baseline (797.303 us; speedup 1.0000x reference)
//
#include <hip/hip_runtime.h>
#include <math.h>

// PASSED at R14 (bit-exact vs np ref). Pinned reference emulation:
//  - einsum: SOP fl(fl(w0x0)+fl(w1x1))  (no FMA)
//  - reduce: numpy BUFFERED reduce: per channel, 25 chunks of 8192; chunk =
//    64 leaves of 128-elem 8-accumulator blocks combined by balanced tree;
//    chunks accumulated sequentially. var = two-pass. rstd = fdiv(1,fsqrt).
//  - LIF fp32 chain with each op rounded.
// R15: parallelize stats (256 us -> target ~40 us) with IDENTICAL rounding:
//  k_bs*: one thread per 128-elem block-sum (409600 threads/pass),
//  k_comb*: one block per channel, thread 0 replays tree+chain exactly.
//  Block-sums staged in d_out (scratch; k_main fully overwrites later).
constexpr int T = 16, B = 512, C = 2, V = 25, E = 256;
constexpr int EV  = E * V;           // 6400
constexpr int BEV = B * EV;          // 3,276,800
constexpr int XT  = B * C * V;       // 25600 floats between t-slices of x
constexpr int NB  = 1600;            // 128-element blocks per channel
constexpr int CHUNKS = 25;           // 204800 / 8192
constexpr int BPC = 64;              // 128-blocks per chunk
constexpr float NF = 204800.0f;

#define WS_M32(ws) ((float*)(ws))
#define WS_R32(ws) ((float*)(ws) + E)

// ---- stage 1a: per-(e,p) 128-element block-sum of y (8-acc pattern) ----
// p in [0,1600); elements q = p*128 + k, k=0..127; acc r[k&7], order-exact.
__global__ void __launch_bounds__(256) k_bs1(const float* __restrict__ x,
                                             const float* __restrict__ W,
                                             float* __restrict__ bs) {
    int e = blockIdx.x;
    int p = blockIdx.y * 200 + threadIdx.x;
    if (threadIdx.x >= 200 || p >= NB) return;
    float w0 = W[e * 2 + 0];
    float w1 = W[e * 2 + 1];
    int q0  = p * 128;
    int row = q0 / 25;
    int v   = q0 - row * 25;
    int bse = row * 50 + v;
    float r[8] = {0,0,0,0,0,0,0,0};
    bool first = true;
    for (int k = 0; k < 128; k++) {
        float y = __fadd_rn(__fmul_rn(w0, x[bse]), __fmul_rn(w1, x[bse + 25]));
        int j = k & 7;
        r[j] = (k < 8) ? y : __fadd_rn(r[j], y);
        v++; bse++;
        if (v == 25) { v = 0; bse += 25; }
    }
    (void)first;
    bs[e * NB + p] = __fadd_rn(__fadd_rn(__fadd_rn(r[0],r[1]), __fadd_rn(r[2],r[3])),
                               __fadd_rn(__fadd_rn(r[4],r[5]), __fadd_rn(r[6],r[7])));
}

// ---- stage 1b: per-(e,p) 128-element block-sum of (y-mean)^2 ----
__global__ void __launch_bounds__(256) k_bs2(const float* __restrict__ x,
                                             const float* __restrict__ W,
                                             const float* __restrict__ ws,
                                             float* __restrict__ bs) {
    int e = blockIdx.x;
    int p = blockIdx.y * 200 + threadIdx.x;
    if (threadIdx.x >= 200 || p >= NB) return;
    float w0 = W[e * 2 + 0];
    float w1 = W[e * 2 + 1];
    float mn = WS_M32(ws)[e];
    int q0  = p * 128;
    int row = q0 / 25;
    int v   = q0 - row * 25;
    int bse = row * 50 + v;
    float r[8] = {0,0,0,0,0,0,0,0};
    for (int k = 0; k < 128; k++) {
        float y = __fadd_rn(__fmul_rn(w0, x[bse]), __fmul_rn(w1, x[bse + 25]));
        float d = __fsub_rn(y, mn);
        float c = __fmul_rn(d, d);
        int j = k & 7;
        r[j] = (k < 8) ? c : __fadd_rn(r[j], c);
        v++; bse++;
        if (v == 25) { v = 0; bse += 25; }
    }
    bs[e * NB + p] = __fadd_rn(__fadd_rn(__fadd_rn(r[0],r[1]), __fadd_rn(r[2],r[3])),
                               __fadd_rn(__fadd_rn(r[4],r[5]), __fadd_rn(r[6],r[7])));
}

// ---- stage 2: per-channel serial combine (exact tree+chain replay) ----
template<int WHICH>
__global__ void __launch_bounds__(256) k_comb(const float* __restrict__ bs,
                                              float* __restrict__ ws) {
    __shared__ float cb[NB];
    int e = blockIdx.x;
    for (int i = threadIdx.x; i < NB; i += 256) cb[i] = bs[e * NB + i];
    __syncthreads();
    if (threadIdx.x == 0) {
        float acc = 0.0f;                       // identity init
        for (int c = 0; c < CHUNKS; c++) {
            float t[BPC];
            for (int i = 0; i < BPC; i++) t[i] = cb[c * BPC + i];
            for (int m = BPC / 2; m >= 1; m >>= 1)   // balanced tree == numpy
                for (int i = 0; i < m; i++)
                    t[i] = __fadd_rn(t[2 * i], t[2 * i + 1]);
            acc = __fadd_rn(acc, t[0]);              // sequential chunk chain
        }
        if (WHICH == 0) {
            WS_M32(ws)[e] = __fdiv_rn(acc, NF);      // mean
        } else {
            float var = __fdiv_rn(acc, NF);
            WS_R32(ws)[e] = __fdiv_rn(1.0f, __fsqrt_rn(__fadd_rn(var, 1e-5f)));
        }
    }
}

// ---- stage 3: LIF + BN apply + spike stores (unchanged from R14) ----
__global__ void __launch_bounds__(256) k_main(const float* __restrict__ x,
                                              const float* __restrict__ W,
                                              const float* __restrict__ g,
                                              const float* __restrict__ bb,
                                              const float* __restrict__ ws,
                                              float* __restrict__ out) {
    int idx = blockIdx.x * 256 + threadIdx.x;   // grid covers BEV exactly
    int b   = idx / EV;
    int rem = idx - b * EV;
    int e   = rem / V;
    int v   = rem - e * V;
    float w0 = W[e * 2 + 0];
    float w1 = W[e * 2 + 1];
    float mn = WS_M32(ws)[e];
    float rs = WS_R32(ws)[e];
    float ga = g[e];                 // == 1.0f: exact no-op
    float be = bb[e];                // == 0.0f: exact no-op
    int xb = b * (C * V) + v;
    float vm = 0.0f;
    #pragma unroll
    for (int t = 0; t < T; t++) {
        float x0 = x[xb + t * XT];
        float x1 = x[xb + t * XT + V];
        float y = __fadd_rn(__fmul_rn(w0, x0), __fmul_rn(w1, x1)); // einsum SOP
        y = __fmul_rn(__fsub_rn(y, mn), rs);                       // (y-mean)*rstd
        y = __fadd_rn(__fmul_rn(y, ga), be);                       // *gamma+beta
        float d = __fmul_rn(__fsub_rn(y, vm), 0.5f);               // (y-v)/2.0
        vm = __fadd_rn(vm, d);                                     // v += ...
        bool sp = (vm >= 1.0f);
        out[(size_t)t * BEV + idx] = sp ? 1.0f : 0.0f;
        if (sp) vm = 0.0f;                                         // hard reset
    }
}

extern "C" void kernel_launch(void* const* d_in, const int* in_sizes, int n_in,
                              void* d_out, int out_size, void* d_ws, size_t ws_size,
                              hipStream_t stream) {
    (void)in_sizes; (void)n_in; (void)out_size; (void)ws_size;
    const float* x  = (const float*)d_in[0];
    const float* W  = (const float*)d_in[1];
    const float* g  = (const float*)d_in[2];
    const float* bb = (const float*)d_in[3];
    float* ws = (float*)d_ws;        // 2 KB: mean[256], rstd[256]
    float* bs = (float*)d_out;       // scratch: 256*1600 floats (1.6 MB);
                                     // k_main fully overwrites d_out after.

    dim3 gbs(E, 8);
    k_bs1 <<<gbs, 256, 0, stream>>>(x, W, bs);
    k_comb<0><<<E, 256, 0, stream>>>(bs, ws);
    k_bs2 <<<gbs, 256, 0, stream>>>(x, W, ws, bs);
    k_comb<1><<<E, 256, 0, stream>>>(bs, ws);
    k_main<<<BEV / 256, 256, 0, stream>>>(x, W, g, bb, ws, (float*)d_out);
}

// Round 16
// 264.882 us; speedup vs baseline: 3.0100x; 3.0100x over previous
//
#include <hip/hip_runtime.h>
#include <math.h>

// Bit-exact np-ref emulation (pinned R14):
//  - einsum: SOP fl(fl(w0x0)+fl(w1x1))  (no FMA)
//  - reduce: numpy BUFFERED reduce: per channel, 25 chunks of 8192; chunk =
//    64 leaves of 128-elem 8-accumulator blocks, balanced tree; chunks
//    accumulated sequentially. var two-pass. rstd = fdiv(1,fsqrt(var+eps)).
//  - LIF fp32 chain, each op rounded.
// R16: restructure stats for memory behavior (rounding order IDENTICAL):
//  one workgroup per 128-elem q-block, one THREAD PER CHANNEL; x-rows staged
//  in LDS once (coalesced) and read as wave-broadcasts; bs stores coalesced.
constexpr int T = 16, B = 512, C = 2, V = 25, E = 256;
constexpr int EV  = E * V;           // 6400
constexpr int BEV = B * EV;          // 3,276,800
constexpr int XT  = B * C * V;       // 25600 floats between t-slices of x
constexpr int NB  = 1600;            // 128-element blocks per channel
constexpr int CHUNKS = 25;           // 204800 / 8192
constexpr int BPC = 64;              // 128-blocks per chunk
constexpr int NROWS = 7;             // max (t,b)-rows touched by a 128-block
constexpr float NF = 204800.0f;

#define WS_M32(ws) ((float*)(ws))
#define WS_R32(ws) ((float*)(ws) + E)

// ---- stage 1: per-(p,e) 128-element block-sum; bs layout [p][e] ----
// PASS=0: sum(y). PASS=1: sum((y-mean)^2).
template<int PASS>
__global__ void __launch_bounds__(256) k_bs(const float* __restrict__ x,
                                            const float* __restrict__ W,
                                            const float* __restrict__ ws,
                                            float* __restrict__ bs) {
    __shared__ float sx[NROWS * 50];
    int p  = blockIdx.x;             // q-block [p*128, p*128+128)
    int q0 = p * 128;
    int row_lo = q0 / 25;
    // stage rows row_lo .. row_lo+6 (guarded), coalesced
    for (int i = threadIdx.x; i < NROWS * 50; i += 256) {
        int r = i / 50;
        if (row_lo + r < 8192) sx[i] = x[(row_lo + r) * 50 + (i - r * 50)];
    }
    __syncthreads();

    int e = threadIdx.x;             // one thread per channel
    float w0 = W[e * 2 + 0];
    float w1 = W[e * 2 + 1];
    float mn = (PASS == 1) ? WS_M32(ws)[e] : 0.0f;

    int v   = q0 - row_lo * 25;      // in-row position
    int off = v;                     // sx offset = (row-row_lo)*50 + v
    float r[8];
    #pragma unroll
    for (int k = 0; k < 128; k++) {
        float y = __fadd_rn(__fmul_rn(w0, sx[off]), __fmul_rn(w1, sx[off + 25]));
        if (PASS == 1) {
            float d = __fsub_rn(y, mn);
            y = __fmul_rn(d, d);
        }
        int j = k & 7;
        r[j] = (k < 8) ? y : __fadd_rn(r[j], y);   // numpy 8-acc pattern
        v++; off++;
        if (v == 25) { v = 0; off += 25; }
    }
    bs[p * 256 + e] =                                  // coalesced store
        __fadd_rn(__fadd_rn(__fadd_rn(r[0], r[1]), __fadd_rn(r[2], r[3])),
                  __fadd_rn(__fadd_rn(r[4], r[5]), __fadd_rn(r[6], r[7])));
}

// ---- stage 2: per-channel serial combine (exact tree+chain replay) ----
template<int WHICH>
__global__ void __launch_bounds__(256) k_comb(const float* __restrict__ bs,
                                              float* __restrict__ ws) {
    __shared__ float cb[NB];
    int e = blockIdx.x;
    for (int i = threadIdx.x; i < NB; i += 256) cb[i] = bs[i * 256 + e];
    __syncthreads();
    if (threadIdx.x == 0) {
        float acc = 0.0f;                            // identity init
        for (int c = 0; c < CHUNKS; c++) {
            float t[BPC];
            for (int i = 0; i < BPC; i++) t[i] = cb[c * BPC + i];
            for (int m = BPC / 2; m >= 1; m >>= 1)   // balanced tree == numpy
                for (int i = 0; i < m; i++)
                    t[i] = __fadd_rn(t[2 * i], t[2 * i + 1]);
            acc = __fadd_rn(acc, t[0]);              // sequential chunk chain
        }
        if (WHICH == 0) {
            WS_M32(ws)[e] = __fdiv_rn(acc, NF);      // mean
        } else {
            float var = __fdiv_rn(acc, NF);
            WS_R32(ws)[e] = __fdiv_rn(1.0f, __fsqrt_rn(__fadd_rn(var, 1e-5f)));
        }
    }
}

// ---- stage 3: LIF + BN apply + spike stores (unchanged, known-correct) ----
__global__ void __launch_bounds__(256) k_main(const float* __restrict__ x,
                                              const float* __restrict__ W,
                                              const float* __restrict__ g,
                                              const float* __restrict__ bb,
                                              const float* __restrict__ ws,
                                              float* __restrict__ out) {
    int idx = blockIdx.x * 256 + threadIdx.x;   // grid covers BEV exactly
    int b   = idx / EV;
    int rem = idx - b * EV;
    int e   = rem / V;
    int v   = rem - e * V;
    float w0 = W[e * 2 + 0];
    float w1 = W[e * 2 + 1];
    float mn = WS_M32(ws)[e];
    float rs = WS_R32(ws)[e];
    float ga = g[e];                 // == 1.0f: exact no-op
    float be = bb[e];                // == 0.0f: exact no-op
    int xb = b * (C * V) + v;
    float vm = 0.0f;
    #pragma unroll
    for (int t = 0; t < T; t++) {
        float x0 = x[xb + t * XT];
        float x1 = x[xb + t * XT + V];
        float y = __fadd_rn(__fmul_rn(w0, x0), __fmul_rn(w1, x1)); // einsum SOP
        y = __fmul_rn(__fsub_rn(y, mn), rs);                       // (y-mean)*rstd
        y = __fadd_rn(__fmul_rn(y, ga), be);                       // *gamma+beta
        float d = __fmul_rn(__fsub_rn(y, vm), 0.5f);               // (y-v)/2.0
        vm = __fadd_rn(vm, d);                                     // v += ...
        bool sp = (vm >= 1.0f);
        out[(size_t)t * BEV + idx] = sp ? 1.0f : 0.0f;
        if (sp) vm = 0.0f;                                         // hard reset
    }
}

extern "C" void kernel_launch(void* const* d_in, const int* in_sizes, int n_in,
                              void* d_out, int out_size, void* d_ws, size_t ws_size,
                              hipStream_t stream) {
    (void)in_sizes; (void)n_in; (void)out_size; (void)ws_size;
    const float* x  = (const float*)d_in[0];
    const float* W  = (const float*)d_in[1];
    const float* g  = (const float*)d_in[2];
    const float* bb = (const float*)d_in[3];
    float* ws = (float*)d_ws;        // 2 KB: mean[256], rstd[256]
    float* bs = (float*)d_out;       // scratch 1.6 MB; k_main overwrites all

    k_bs<0><<<NB, 256, 0, stream>>>(x, W, ws, bs);
    k_comb<0><<<E, 256, 0, stream>>>(bs, ws);
    k_bs<1><<<NB, 256, 0, stream>>>(x, W, ws, bs);
    k_comb<1><<<E, 256, 0, stream>>>(bs, ws);
    k_main<<<BEV / 256, 256, 0, stream>>>(x, W, g, bb, ws, (float*)d_out);
}

// Round 17
// 257.777 us; speedup vs baseline: 3.0930x; 1.0276x over previous
//
#include <hip/hip_runtime.h>
#include <math.h>

// Bit-exact np-ref emulation (pinned R14, PASSING since):
//  - einsum: SOP fl(fl(w0x0)+fl(w1x1))  (no FMA)
//  - reduce: numpy BUFFERED reduce: per channel, 25 chunks of 8192; chunk =
//    64 leaves of 128-elem 8-acc blocks, balanced tree; chunks sequential.
//    var two-pass. rstd = fdiv(1,fsqrt(var+eps)). LIF fp32, each op rounded.
// R17 (data movement only; rounding order IDENTICAL):
//  - k_comb: register-resident unrolled tree (was scratch-thrashed), 25
//    parallel chunk-threads + serial 25-chain on thread 0.
//  - k_main: per-block LDS stage of its b's 800 x-floats (reads become LDS
//    broadcasts); nontemporal spike stores (bypass L2).
constexpr int T = 16, B = 512, C = 2, V = 25, E = 256;
constexpr int EV  = E * V;           // 6400
constexpr int BEV = B * EV;          // 3,276,800
constexpr int XT  = B * C * V;       // 25600 floats between t-slices of x
constexpr int NB  = 1600;            // 128-element blocks per channel
constexpr int CHUNKS = 25;           // 204800 / 8192
constexpr int BPC = 64;              // 128-blocks per chunk
constexpr int NROWS = 7;             // max (t,b)-rows touched by a 128-block
constexpr float NF = 204800.0f;

#define WS_M32(ws) ((float*)(ws))
#define WS_R32(ws) ((float*)(ws) + E)

// ---- stage 1: per-(p,e) 128-element block-sum; bs layout [p][e] ----
template<int PASS>
__global__ void __launch_bounds__(256) k_bs(const float* __restrict__ x,
                                            const float* __restrict__ W,
                                            const float* __restrict__ ws,
                                            float* __restrict__ bs) {
    __shared__ float sx[NROWS * 50];
    int p  = blockIdx.x;             // q-block [p*128, p*128+128)
    int q0 = p * 128;
    int row_lo = q0 / 25;
    for (int i = threadIdx.x; i < NROWS * 50; i += 256) {
        int r = i / 50;
        if (row_lo + r < 8192) sx[i] = x[(row_lo + r) * 50 + (i - r * 50)];
    }
    __syncthreads();

    int e = threadIdx.x;             // one thread per channel
    float w0 = W[e * 2 + 0];
    float w1 = W[e * 2 + 1];
    float mn = (PASS == 1) ? WS_M32(ws)[e] : 0.0f;

    int v   = q0 - row_lo * 25;
    int off = v;
    float r[8];
    #pragma unroll
    for (int k = 0; k < 128; k++) {
        float y = __fadd_rn(__fmul_rn(w0, sx[off]), __fmul_rn(w1, sx[off + 25]));
        if (PASS == 1) {
            float d = __fsub_rn(y, mn);
            y = __fmul_rn(d, d);
        }
        int j = k & 7;
        r[j] = (k < 8) ? y : __fadd_rn(r[j], y);   // numpy 8-acc pattern
        v++; off++;
        if (v == 25) { v = 0; off += 25; }
    }
    bs[p * 256 + e] =
        __fadd_rn(__fadd_rn(__fadd_rn(r[0], r[1]), __fadd_rn(r[2], r[3])),
                  __fadd_rn(__fadd_rn(r[4], r[5]), __fadd_rn(r[6], r[7])));
}

// ---- stage 2: per-channel combine; register tree (no scratch) ----
template<int WHICH>
__global__ void __launch_bounds__(64) k_comb(const float* __restrict__ bs,
                                             float* __restrict__ ws) {
    __shared__ float cb[NB];
    __shared__ float csum[CHUNKS];
    int e = blockIdx.x;
    for (int i = threadIdx.x; i < NB; i += 64) cb[i] = bs[i * 256 + e];
    __syncthreads();
    if (threadIdx.x < CHUNKS) {
        int c = threadIdx.x;
        float t[BPC];                       // fully-unrolled -> VGPRs
        #pragma unroll
        for (int i = 0; i < BPC; i++) t[i] = cb[c * BPC + i];
        #pragma unroll
        for (int m = BPC / 2; m >= 1; m >>= 1) {    // balanced tree == numpy
            #pragma unroll
            for (int i = 0; i < m; i++)
                t[i] = __fadd_rn(t[2 * i], t[2 * i + 1]);
        }
        csum[c] = t[0];
    }
    __syncthreads();
    if (threadIdx.x == 0) {
        float acc = 0.0f;                   // identity init
        #pragma unroll
        for (int c = 0; c < CHUNKS; c++) acc = __fadd_rn(acc, csum[c]);
        if (WHICH == 0) {
            WS_M32(ws)[e] = __fdiv_rn(acc, NF);
        } else {
            float var = __fdiv_rn(acc, NF);
            WS_R32(ws)[e] = __fdiv_rn(1.0f, __fsqrt_rn(__fadd_rn(var, 1e-5f)));
        }
    }
}

// ---- stage 3: LIF + BN apply; LDS-staged x, nontemporal stores ----
__global__ void __launch_bounds__(256) k_main(const float* __restrict__ x,
                                              const float* __restrict__ W,
                                              const float* __restrict__ g,
                                              const float* __restrict__ bb,
                                              const float* __restrict__ ws,
                                              float* __restrict__ out) {
    __shared__ float sx[T * 50];     // this block's b: x[b,t,c,v], 3.2 KB
    int blk = blockIdx.x;            // 12800 blocks; 25 blocks per b
    int b   = blk / 25;
    int seg = blk - b * 25;
    for (int i = threadIdx.x; i < T * 50; i += 256) {
        int t = i / 50;
        sx[i] = x[b * 50 + t * XT + (i - t * 50)];
    }
    __syncthreads();

    int idx = blk * 256 + threadIdx.x;          // global (b,e,v) index
    int rem = seg * 256 + threadIdx.x;          // within EV
    int e   = rem / V;
    int v   = rem - e * V;
    float w0 = W[e * 2 + 0];
    float w1 = W[e * 2 + 1];
    float mn = WS_M32(ws)[e];
    float rs = WS_R32(ws)[e];
    float ga = g[e];                 // == 1.0f: exact no-op
    float be = bb[e];                // == 0.0f: exact no-op
    float vm = 0.0f;
    #pragma unroll
    for (int t = 0; t < T; t++) {
        float x0 = sx[t * 50 + v];
        float x1 = sx[t * 50 + 25 + v];
        float y = __fadd_rn(__fmul_rn(w0, x0), __fmul_rn(w1, x1)); // einsum SOP
        y = __fmul_rn(__fsub_rn(y, mn), rs);                       // (y-mean)*rstd
        y = __fadd_rn(__fmul_rn(y, ga), be);                       // *gamma+beta
        float d = __fmul_rn(__fsub_rn(y, vm), 0.5f);               // (y-v)/2.0
        vm = __fadd_rn(vm, d);                                     // v += ...
        bool sp = (vm >= 1.0f);
        __builtin_nontemporal_store(sp ? 1.0f : 0.0f,
                                    &out[(size_t)t * BEV + idx]);
        if (sp) vm = 0.0f;                                         // hard reset
    }
}

extern "C" void kernel_launch(void* const* d_in, const int* in_sizes, int n_in,
                              void* d_out, int out_size, void* d_ws, size_t ws_size,
                              hipStream_t stream) {
    (void)in_sizes; (void)n_in; (void)out_size; (void)ws_size;
    const float* x  = (const float*)d_in[0];
    const float* W  = (const float*)d_in[1];
    const float* g  = (const float*)d_in[2];
    const float* bb = (const float*)d_in[3];
    float* ws = (float*)d_ws;        // 2 KB: mean[256], rstd[256]
    float* bs = (float*)d_out;       // scratch 1.6 MB; k_main overwrites all

    k_bs<0><<<NB, 256, 0, stream>>>(x, W, ws, bs);
    k_comb<0><<<E, 64, 0, stream>>>(bs, ws);
    k_bs<1><<<NB, 256, 0, stream>>>(x, W, ws, bs);
    k_comb<1><<<E, 64, 0, stream>>>(bs, ws);
    k_main<<<BEV / 256, 256, 0, stream>>>(x, W, g, bb, ws, (float*)d_out);
}